// Round 7
// baseline (313.078 us; speedup 1.0000x reference)
//
#include <hip/hip_runtime.h>
#include <cstdint>
#include <cstddef>

#define B_   4
#define N_   1024
#define D_   2048
#define HQ_  16
#define HKV_ 4
#define DH_  128
#define E_   3072

#define SCALE_ 0.08838834764831845  // 128^-0.5

typedef __attribute__((ext_vector_type(8))) short frag16;
typedef __attribute__((ext_vector_type(4))) float fragf4;
#define MFMA16(a, b, c) __builtin_amdgcn_mfma_f32_16x16x32_bf16(a, b, c, 0, 0, 0)

__device__ __forceinline__ short f2bf(float f) {
  union { float f; uint32_t u; } a; a.f = f;
  uint32_t r = (a.u + 0x7fffu + ((a.u >> 16) & 1u)) >> 16;  // RNE
  return (short)r;
}
__device__ __forceinline__ short f2bf_t(float f) {  // truncate (p>=0)
  union { float f; uint32_t u; } a; a.f = f;
  return (short)(a.u >> 16);
}
__device__ __forceinline__ void async_copy16(const void* g, void* l) {
  __builtin_amdgcn_global_load_lds(
      (const __attribute__((address_space(1))) void*)g,
      (__attribute__((address_space(3))) void*)l, 16, 0, 0);
}

// ---------------------------------------------------------------------------
// fused fp32 -> bf16 conversion for all three tensors (one launch)
// ---------------------------------------------------------------------------
__global__ __launch_bounds__(256) void f2bf3_kernel(
    const float* __restrict__ s0, short* __restrict__ d0, int b0,
    const float* __restrict__ s1, short* __restrict__ d1, int b1,
    const float* __restrict__ s2, short* __restrict__ d2) {
  int bx = blockIdx.x;
  const float* s; short* d;
  if (bx < b0)           { s = s0; d = d0; }
  else if (bx < b0 + b1) { s = s1; d = d1; bx -= b0; }
  else                   { s = s2; d = d2; bx -= b0 + b1; }
  const int i = (bx * 256 + threadIdx.x) * 8;
  float4 a = *(const float4*)(s + i);
  float4 b = *(const float4*)(s + i + 4);
  union { frag16 f; short sh[8]; } u;
  u.sh[0] = f2bf(a.x); u.sh[1] = f2bf(a.y); u.sh[2] = f2bf(a.z); u.sh[3] = f2bf(a.w);
  u.sh[4] = f2bf(b.x); u.sh[5] = f2bf(b.y); u.sh[6] = f2bf(b.z); u.sh[7] = f2bf(b.w);
  *(frag16*)(d + i) = u.f;
}

// ---------------------------------------------------------------------------
// bf16 MFMA GEMM (unchanged from round 6 — at the m97 plateau)
// ---------------------------------------------------------------------------
template <typename OutT>
__global__ __launch_bounds__(256) void gemm_mfma(const short* __restrict__ A,
                                                 const short* __restrict__ Wt,
                                                 OutT* __restrict__ C,
                                                 int Nc, int K, int ncpx) {
  __shared__ __align__(16) short As[128][64];
  __shared__ __align__(16) short Bs[128][64];

  const int bid = blockIdx.x;
  const int xcd = bid & 7, j = bid >> 3;
  const int m0 = (j & 31) * 128;
  const int n0 = (xcd * ncpx + (j >> 5)) * 128;

  const int tid = threadIdx.x;
  const int lane = tid & 63;
  const int w = tid >> 6;
  const int ln = lane & 15, g = lane >> 4;
  const int wm = (w >> 1) * 64, wn = (w & 1) * 64;

  const int srow = lane >> 3;
  const int schunk = ((lane & 7) ^ srow) * 8;
  const int l7 = ln & 7;

  fragf4 acc[4][4];
#pragma unroll
  for (int i = 0; i < 4; ++i)
#pragma unroll
    for (int jj = 0; jj < 4; ++jj) acc[i][jj] = (fragf4){0.f, 0.f, 0.f, 0.f};

  for (int k0 = 0; k0 < K; k0 += 64) {
    __syncthreads();
#pragma unroll
    for (int i = 0; i < 4; ++i) {
      const int rbase = w * 32 + i * 8;
      const int r = rbase + srow;
      async_copy16(A  + (size_t)(m0 + r) * K + k0 + schunk, &As[rbase][0]);
      async_copy16(Wt + (size_t)(n0 + r) * K + k0 + schunk, &Bs[rbase][0]);
    }
    __syncthreads();

    frag16 af[2][4], bf[2][4];
#pragma unroll
    for (int c = 0; c < 2; ++c) {
      const int pc = (((c << 2) | g) ^ l7) * 8;
#pragma unroll
      for (int t = 0; t < 4; ++t) {
        af[c][t] = *(const frag16*)&As[wm + t * 16 + ln][pc];
        bf[c][t] = *(const frag16*)&Bs[wn + t * 16 + ln][pc];
      }
    }
#pragma unroll
    for (int c = 0; c < 2; ++c)
#pragma unroll
      for (int i = 0; i < 4; ++i)
#pragma unroll
        for (int jj = 0; jj < 4; ++jj)
          acc[i][jj] = MFMA16(af[c][i], bf[c][jj], acc[i][jj]);
  }

#pragma unroll
  for (int i = 0; i < 4; ++i) {
#pragma unroll
    for (int jj = 0; jj < 4; ++jj) {
#pragma unroll
      for (int r = 0; r < 4; ++r) {
        const size_t idx = (size_t)(m0 + wm + i * 16 + 4 * g + r) * Nc +
                           (n0 + wn + jj * 16 + ln);
        if constexpr (sizeof(OutT) == 2) C[idx] = f2bf(acc[i][jj][r]);
        else                             C[idx] = acc[i][jj][r];
      }
    }
  }
}

// ---------------------------------------------------------------------------
// Fused RMSNorm+RoPE + V-transpose (unchanged from round 6)
// ---------------------------------------------------------------------------
__global__ __launch_bounds__(256) void normrope_vt(short* __restrict__ qkvb,
                                                   short* __restrict__ vtg,
                                                   const int* __restrict__ pos,
                                                   const float* __restrict__ qw,
                                                   const float* __restrict__ kw,
                                                   int nrB) {
  __shared__ short T[128 * 72];
  const int tid = threadIdx.x;

  if ((int)blockIdx.x < nrB) {
    const int gid = blockIdx.x * 256 + tid;
    const int lane = gid & 63;
    const int wid = gid >> 6;
    const int hh = wid % (HQ_ + HKV_);
    const int n  = (wid / (HQ_ + HKV_)) % N_;
    const int b  = wid / ((HQ_ + HKV_) * N_);

    int eoff; const float* w;
    if (hh < HQ_) { eoff = hh * DH_;              w = qw; }
    else          { eoff = D_ + (hh - HQ_) * DH_; w = kw; }

    short* base = qkvb + ((size_t)b * N_ + n) * E_ + eoff;
    union { uint32_t u; float f; } c1, c2;
    c1.u = ((uint32_t)(uint16_t)base[lane]) << 16;
    c2.u = ((uint32_t)(uint16_t)base[64 + lane]) << 16;
    float t1 = c1.f, t2 = c2.f;

    float ss = t1 * t1 + t2 * t2;
#pragma unroll
    for (int off = 32; off; off >>= 1) ss += __shfl_xor(ss, off);
    const float r = rsqrtf(ss * (1.0f / 128.0f) + 1.1920928955078125e-07f);
    t1 = t1 * r * w[lane];
    t2 = t2 * r * w[64 + lane];

    const float invf = (float)exp2(-(double)lane * 0.20762050593046014);
    const float ang = (float)pos[n] * invf;
    const float c = cosf(ang), s = sinf(ang);
    base[lane]      = f2bf(t1 * c - t2 * s);
    base[64 + lane] = f2bf(t2 * c + t1 * s);
  } else {
    const int idx = blockIdx.x - nrB;
    const int n0 = (idx & 15) * 64, kh = (idx >> 4) & 3, b = idx >> 6;
    {
      const int r = tid & 63, dc = (tid >> 6) * 32;
      const short* src = qkvb + ((size_t)b * N_ + n0 + r) * E_ + 2560 + kh * DH_ + dc;
      union { frag16 f; short s[8]; } u;
#pragma unroll
      for (int i = 0; i < 4; ++i) {
        u.f = *(const frag16*)(src + 8 * i);
#pragma unroll
        for (int jj = 0; jj < 8; ++jj) T[(dc + 8 * i + jj) * 72 + r] = u.s[jj];
      }
    }
    __syncthreads();
    {
      const int d = tid & 127, e = tid >> 7;
      short* dst = vtg + ((size_t)(b * HKV_ + kh) * DH_ + d) * N_ + n0 + e * 32;
#pragma unroll
      for (int i = 0; i < 4; ++i)
        *(frag16*)(dst + 8 * i) = *(const frag16*)&T[d * 72 + e * 32 + 8 * i];
    }
  }
}

// ---------------------------------------------------------------------------
// bf16-MFMA flash attention v3: 32 q-rows/wave, XOR bank swizzle, fixed-max
// softmax, l via all-ones B-frag MFMA.
// Grid 512: qt2 = 31-(bx>>4) (LPT), (kh,b) = bx&15. 4 waves = 4 q-heads.
// LDS: Ks 64x128 @0 | Vt 128x64 @8192 | Ps 4 x 32 x 88 @16384 (55.3 KB).
// K row = 256 B, V row = 128 B; 16-B chunk c of row r at phys c^(r&7).
// ---------------------------------------------------------------------------
__global__ __launch_bounds__(256) void attn_mfma(const short* __restrict__ qkvb,
                                                 const short* __restrict__ vtg,
                                                 short* __restrict__ yb) {
  const int bx = blockIdx.x;
  const int qt2 = 31 - (bx >> 4);
  const int id = bx & 15;
  const int kh = id & 3, b = id >> 2;
  const int q0 = qt2 * 32;

  __shared__ __align__(16) short lds_[27648];
  const int VT0 = 8192, PS0 = 16384;

  const int tid = threadIdx.x;
  const int lane = tid & 63;
  const int w = tid >> 6;
  const int ln = lane & 15, g = lane >> 4, g8 = g * 8, l7 = ln & 7;
  const int h = kh * 4 + w;
  const int psw = PS0 + w * 2816;  // 32 rows x 88

  const short* qb = qkvb + (size_t)b * N_ * E_ + h * DH_;
  const short* kb = qkvb + (size_t)b * N_ * E_ + D_ + kh * DH_;
  const short* vt = vtg + (size_t)(b * HKV_ + kh) * DH_ * N_;

  frag16 qf[2][4];
#pragma unroll
  for (int t = 0; t < 2; ++t) {
    const short* qrow = qb + (size_t)(q0 + 16 * t + ln) * E_ + g8;
#pragma unroll
    for (int c = 0; c < 4; ++c) qf[t][c] = *(const frag16*)(qrow + c * 32);
  }

  frag16 ones;
#pragma unroll
  for (int j = 0; j < 8; ++j) ones[j] = (short)0x3F80;

  fragf4 o[2][8], ol[2];
#pragma unroll
  for (int t = 0; t < 2; ++t) {
    ol[t] = (fragf4){0.f, 0.f, 0.f, 0.f};
#pragma unroll
    for (int dt = 0; dt < 8; ++dt) o[t][dt] = (fragf4){0.f, 0.f, 0.f, 0.f};
  }

  const float SC2 = (float)(SCALE_ * 1.4426950408889634);
  const float MB2 = (float)(12.0 * 1.4426950408889634);

  // staging coords
  const int krow = tid >> 2, kgrp = tid & 3;        // K: 4 thr/row, 4 chunks ea
  const int vrow = tid >> 1, vgrp = tid & 1;        // V: 2 thr/row, 4 chunks ea

  const int ntiles = (q0 + 95) >> 6;
  for (int kt = 0; kt < ntiles; ++kt) {
    const int kbase = kt * 64;
    __syncthreads();
    {  // stage K: 64 rows x 128 shorts
      const short* src = kb + (size_t)(kbase + krow) * E_ + kgrp * 32;
      const int r7 = krow & 7;
#pragma unroll
      for (int i = 0; i < 4; ++i) {
        const int lc = kgrp * 4 + i;
        *(frag16*)&lds_[krow * 128 + (lc ^ r7) * 8] = *(const frag16*)(src + i * 8);
      }
    }
    {  // stage V^T: 128 rows x 64 shorts
      const short* src = vt + (size_t)vrow * N_ + kbase + vgrp * 32;
      const int r7 = vrow & 7;
#pragma unroll
      for (int i = 0; i < 4; ++i) {
        const int lc = vgrp * 4 + i;
        *(frag16*)&lds_[VT0 + vrow * 64 + (lc ^ r7) * 8] = *(const frag16*)(src + i * 8);
      }
    }
    __syncthreads();

    // ---- QK^T: 32 q-rows x 64 keys; kf shared across both q-tiles ----
    fragf4 s[2][4];
#pragma unroll
    for (int t = 0; t < 2; ++t)
#pragma unroll
      for (int st = 0; st < 4; ++st) s[t][st] = (fragf4){0.f, 0.f, 0.f, 0.f};
#pragma unroll
    for (int c = 0; c < 4; ++c) {
      const int pc = ((c * 4 + g) ^ l7) * 8;
#pragma unroll
      for (int st = 0; st < 4; ++st) {
        frag16 kf = *(const frag16*)&lds_[(st * 16 + ln) * 128 + pc];
        s[0][st] = MFMA16(qf[0][c], kf, s[0][st]);
        s[1][st] = MFMA16(qf[1][c], kf, s[1][st]);
      }
    }

    // ---- fixed-max softmax, P -> LDS (per-wave region) ----
#pragma unroll
    for (int t = 0; t < 2; ++t) {
      const int qbase = q0 + 16 * t;
      const bool full = (kbase + 63) <= qbase;
#pragma unroll
      for (int st = 0; st < 4; ++st) {
        const int kg = kbase + st * 16 + ln;
        const int po = psw + (st >> 1) * 48 + (st & 1) * 16 + ln;
#pragma unroll
        for (int r2 = 0; r2 < 4; ++r2) {
          float sv = s[t][st][r2];
          if (!full && kg > qbase + 4 * g + r2) sv = -1.0e30f;
          const float p = exp2f(fmaf(sv, SC2, -MB2));
          lds_[po + (16 * t + 4 * g + r2) * 88] = f2bf_t(p);
        }
      }
    }

    // ---- PV + l: vf shared across both q-tiles ----
    frag16 pf[2][2];
#pragma unroll
    for (int t = 0; t < 2; ++t)
#pragma unroll
      for (int hh = 0; hh < 2; ++hh)
        pf[t][hh] = *(const frag16*)&lds_[psw + (16 * t + ln) * 88 + hh * 48 + g8];
#pragma unroll
    for (int dt = 0; dt < 8; ++dt) {
#pragma unroll
      for (int hh = 0; hh < 2; ++hh) {
        const int pv = ((hh * 4 + g) ^ l7) * 8;
        frag16 vf = *(const frag16*)&lds_[VT0 + (dt * 16 + ln) * 64 + pv];
        o[0][dt] = MFMA16(pf[0][hh], vf, o[0][dt]);
        o[1][dt] = MFMA16(pf[1][hh], vf, o[1][dt]);
      }
    }
#pragma unroll
    for (int t = 0; t < 2; ++t) {
      ol[t] = MFMA16(pf[t][0], ones, ol[t]);
      ol[t] = MFMA16(pf[t][1], ones, ol[t]);
    }
  }

  // ---- epilogue: ol cols are all equal -> lane-local l, no shuffle ----
#pragma unroll
  for (int t = 0; t < 2; ++t) {
#pragma unroll
    for (int r2 = 0; r2 < 4; ++r2) {
      const float inv = 1.0f / ol[t][r2];
      short* yrow = yb + ((size_t)b * N_ + q0 + 16 * t + 4 * g + r2) * D_ + h * DH_;
#pragma unroll
      for (int dt = 0; dt < 8; ++dt) yrow[dt * 16 + ln] = f2bf(o[t][dt][r2] * inv);
    }
  }
}

// ---------------------------------------------------------------------------
extern "C" void kernel_launch(void* const* d_in, const int* in_sizes, int n_in,
                              void* d_out, int out_size, void* d_ws, size_t ws_size,
                              hipStream_t stream) {
  const float* x     = (const float*)d_in[0];
  const int*   pos   = (const int*)d_in[2];
  const float* w_qkv = (const float*)d_in[3];
  const float* w_out = (const float*)d_in[4];
  const float* qw    = (const float*)d_in[5];
  const float* kw    = (const float*)d_in[6];
  float* out = (float*)d_out;

  short* qkvb = (short*)d_ws;
  short* yb   = qkvb + (size_t)B_ * N_ * E_;
  short* xb   = yb   + (size_t)B_ * N_ * D_;
  short* wqb  = xb   + (size_t)B_ * N_ * D_;
  short* wob  = wqb  + (size_t)E_ * D_;
  short* vtg  = xb;  // alias, used post-gemm1

  const int nx = B_ * N_ * D_, nwq = E_ * D_, nwo = D_ * D_;
  const int bx_ = nx / 2048, bwq = nwq / 2048, bwo = nwo / 2048;
  f2bf3_kernel<<<bx_ + bwq + bwo, 256, 0, stream>>>(
      x, xb, bx_, w_qkv, wqb, bwq, w_out, wob);

  gemm_mfma<short><<<768, 256, 0, stream>>>(xb, wqb, qkvb, E_, D_, 3);

  const int nrB = (B_ * N_ * (HQ_ + HKV_) * 64) / 256;  // 20480
  normrope_vt<<<nrB + 256, 256, 0, stream>>>(qkvb, vtg, pos, qw, kw, nrB);

  attn_mfma<<<512, 256, 0, stream>>>(qkvb, vtg, yb);

  gemm_mfma<float><<<512, 256, 0, stream>>>(yb, wob, out, D_, D_, 2);
}

// Round 8
// 309.700 us; speedup vs baseline: 1.0109x; 1.0109x over previous
//
#include <hip/hip_runtime.h>
#include <cstdint>
#include <cstddef>

#define B_   4
#define N_   1024
#define D_   2048
#define HQ_  16
#define HKV_ 4
#define DH_  128
#define E_   3072

#define SCALE_ 0.08838834764831845  // 128^-0.5

typedef __attribute__((ext_vector_type(8))) short frag16;
typedef __attribute__((ext_vector_type(4))) float fragf4;
#define MFMA16(a, b, c) __builtin_amdgcn_mfma_f32_16x16x32_bf16(a, b, c, 0, 0, 0)

__device__ __forceinline__ short f2bf(float f) {
  union { float f; uint32_t u; } a; a.f = f;
  uint32_t r = (a.u + 0x7fffu + ((a.u >> 16) & 1u)) >> 16;  // RNE
  return (short)r;
}
__device__ __forceinline__ short f2bf_t(float f) {  // truncate (p>=0)
  union { float f; uint32_t u; } a; a.f = f;
  return (short)(a.u >> 16);
}
__device__ __forceinline__ float bf2f(unsigned short s) {
  union { uint32_t u; float f; } a;
  a.u = ((uint32_t)s) << 16;
  return a.f;
}
__device__ __forceinline__ void async_copy16(const void* g, void* l) {
  __builtin_amdgcn_global_load_lds(
      (const __attribute__((address_space(1))) void*)g,
      (__attribute__((address_space(3))) void*)l, 16, 0, 0);
}

// ---------------------------------------------------------------------------
// fused fp32->bf16 conversion (3 tensors) + RoPE cos/sin table, one launch.
// tab[seq*64 + d] = {cos, sin} of pos[seq] * 10000^(-d/64)
// ---------------------------------------------------------------------------
__global__ __launch_bounds__(256) void f2bf3r(
    const float* __restrict__ s0, short* __restrict__ d0, int b0,
    const float* __restrict__ s1, short* __restrict__ d1, int b1,
    const float* __restrict__ s2, short* __restrict__ d2, int b2,
    const int* __restrict__ pos, float2* __restrict__ tab) {
  int bx = blockIdx.x;
  const int btot = b0 + b1 + b2;
  if (bx < btot) {
    const float* s; short* d;
    if (bx < b0)           { s = s0; d = d0; }
    else if (bx < b0 + b1) { s = s1; d = d1; bx -= b0; }
    else                   { s = s2; d = d2; bx -= b0 + b1; }
    const int i = (bx * 256 + threadIdx.x) * 8;
    float4 a = *(const float4*)(s + i);
    float4 b = *(const float4*)(s + i + 4);
    union { frag16 f; short sh[8]; } u;
    u.sh[0] = f2bf(a.x); u.sh[1] = f2bf(a.y); u.sh[2] = f2bf(a.z); u.sh[3] = f2bf(a.w);
    u.sh[4] = f2bf(b.x); u.sh[5] = f2bf(b.y); u.sh[6] = f2bf(b.z); u.sh[7] = f2bf(b.w);
    *(frag16*)(d + i) = u.f;
  } else {
    const int idx = (bx - btot) * 256 + threadIdx.x;  // 0..65535
    const int seq = idx >> 6, dd = idx & 63;
    const float invf = (float)exp2(-(double)dd * 0.20762050593046014);
    const float ang = (float)pos[seq] * invf;
    float2 cs; cs.x = cosf(ang); cs.y = sinf(ang);
    tab[idx] = cs;
  }
}

// ---------------------------------------------------------------------------
// QKV GEMM with fused RMSNorm + RoPE + V-transpose epilogue.
// C-tile 128x128 = 128 seq positions x exactly ONE head (DH=128).
// K-loop identical to the m97-plateau gemm (BK=64, XOR swizzle, async LDS).
// Epilogue: q/k heads -> rowwise rms (shuffle + cross-wave LDS) -> bf16 tile
// -> RoPE pairs (d, d+64) -> qkvb.  v heads -> transposed tile -> vtg.
// ---------------------------------------------------------------------------
__global__ __launch_bounds__(256) void gemm_qkv(
    const short* __restrict__ A, const short* __restrict__ Wt,
    short* __restrict__ qkvb, short* __restrict__ vtg,
    const float2* __restrict__ tab,
    const float* __restrict__ qw, const float* __restrict__ kw) {
  // smem carve: K-loop As[128][64]@0, Bs[128][64]@8192 (shorts)
  //             epilogue tile[128][136]@0, Sred 256 floats @17408
  __shared__ __align__(16) short smem[17920];
  short* As = smem;
  short* Bs = smem + 8192;

  const int bid = blockIdx.x;
  const int xcd = bid & 7, j = bid >> 3;
  const int m0 = (j & 31) * 128;
  const int n0 = (xcd * 3 + (j >> 5)) * 128;

  const int tid = threadIdx.x;
  const int lane = tid & 63;
  const int w = tid >> 6;
  const int ln = lane & 15, g = lane >> 4;
  const int wm = (w >> 1) * 64, wn = (w & 1) * 64;

  const int srow = lane >> 3;
  const int schunk = ((lane & 7) ^ srow) * 8;
  const int l7 = ln & 7;

  fragf4 acc[4][4];
#pragma unroll
  for (int i = 0; i < 4; ++i)
#pragma unroll
    for (int jj = 0; jj < 4; ++jj) acc[i][jj] = (fragf4){0.f, 0.f, 0.f, 0.f};

  for (int k0 = 0; k0 < D_; k0 += 64) {
    __syncthreads();
#pragma unroll
    for (int i = 0; i < 4; ++i) {
      const int rbase = w * 32 + i * 8;
      const int r = rbase + srow;
      async_copy16(A  + (size_t)(m0 + r) * D_ + k0 + schunk, &As[rbase * 64]);
      async_copy16(Wt + (size_t)(n0 + r) * D_ + k0 + schunk, &Bs[rbase * 64]);
    }
    __syncthreads();

    frag16 af[2][4], bf[2][4];
#pragma unroll
    for (int c = 0; c < 2; ++c) {
      const int pc = (((c << 2) | g) ^ l7) * 8;
#pragma unroll
      for (int t = 0; t < 4; ++t) {
        af[c][t] = *(const frag16*)&As[(wm + t * 16 + ln) * 64 + pc];
        bf[c][t] = *(const frag16*)&Bs[(wn + t * 16 + ln) * 64 + pc];
      }
    }
#pragma unroll
    for (int c = 0; c < 2; ++c)
#pragma unroll
      for (int i = 0; i < 4; ++i)
#pragma unroll
        for (int jj = 0; jj < 4; ++jj)
          acc[i][jj] = MFMA16(af[c][i], bf[c][jj], acc[i][jj]);
  }

  // ---------------- fused epilogue ----------------
  const int hh = n0 >> 7;        // head 0..23 (0-15 q, 16-19 k, 20-23 v)
  const int b  = m0 >> 10;
  const int seq0 = m0 & 1023;
  short* T = smem;               // [128][136]
  float* Sred = (float*)&smem[17408];  // [2][128]

  __syncthreads();  // all frag reads done before tile overwrite

  if (hh < 20) {
    // rowwise sum of squares: shuffle over 16-lane group, LDS across waves
    float rs[4][4];
#pragma unroll
    for (int i = 0; i < 4; ++i)
#pragma unroll
      for (int r = 0; r < 4; ++r) {
        float t = 0.f;
#pragma unroll
        for (int jj = 0; jj < 4; ++jj) t += acc[i][jj][r] * acc[i][jj][r];
        rs[i][r] = t;
      }
#pragma unroll
    for (int off = 1; off <= 8; off <<= 1)
#pragma unroll
      for (int i = 0; i < 4; ++i)
#pragma unroll
        for (int r = 0; r < 4; ++r) rs[i][r] += __shfl_xor(rs[i][r], off);
    if (ln == 0) {
#pragma unroll
      for (int i = 0; i < 4; ++i)
#pragma unroll
        for (int r = 0; r < 4; ++r)
          Sred[(w & 1) * 128 + wm + i * 16 + 4 * g + r] = rs[i][r];
    }
    __syncthreads();

    const float* wnv = (hh < 16) ? qw : kw;
    float wv[4];
#pragma unroll
    for (int jj = 0; jj < 4; ++jj) wv[jj] = wnv[wn + jj * 16 + ln];
#pragma unroll
    for (int i = 0; i < 4; ++i)
#pragma unroll
      for (int r = 0; r < 4; ++r) {
        const int row = wm + i * 16 + 4 * g + r;
        const float tot = Sred[row] + Sred[128 + row];
        const float rms = rsqrtf(tot * (1.0f / 128.0f) + 1.1920928955078125e-07f);
#pragma unroll
        for (int jj = 0; jj < 4; ++jj)
          T[row * 136 + wn + jj * 16 + ln] = f2bf(acc[i][jj][r] * rms * wv[jj]);
      }
    __syncthreads();

    // RoPE: pairs (d, d+64), 2 d's per thread, 16 rows per thread
    const int d0 = (tid & 31) * 2, rg = tid >> 5;
#pragma unroll
    for (int rr = 0; rr < 16; ++rr) {
      const int row = rg * 16 + rr;
      ushort2 u1 = *(const ushort2*)&T[row * 136 + d0];
      ushort2 u2 = *(const ushort2*)&T[row * 136 + d0 + 64];
      float4 cs = *(const float4*)&tab[(seq0 + row) * 64 + d0];  // c0,s0,c1,s1
      const float v1a = bf2f(u1.x), v1b = bf2f(u1.y);
      const float v2a = bf2f(u2.x), v2b = bf2f(u2.y);
      ushort2 o1, o2;
      o1.x = (unsigned short)f2bf(v1a * cs.x - v2a * cs.y);
      o1.y = (unsigned short)f2bf(v1b * cs.z - v2b * cs.w);
      o2.x = (unsigned short)f2bf(v2a * cs.x + v1a * cs.y);
      o2.y = (unsigned short)f2bf(v2b * cs.z + v1b * cs.w);
      short* dst = qkvb + ((size_t)b * N_ + seq0 + row) * E_ + hh * DH_ + d0;
      *(ushort2*)dst = o1;
      *(ushort2*)(dst + 64) = o2;
    }
  } else {
    // v head: write tile TRANSPOSED [d][seq], then coalesced rows to vtg
#pragma unroll
    for (int i = 0; i < 4; ++i)
#pragma unroll
      for (int jj = 0; jj < 4; ++jj)
#pragma unroll
        for (int r = 0; r < 4; ++r)
          T[(wn + jj * 16 + ln) * 136 + wm + i * 16 + 4 * g + r] =
              f2bf(acc[i][jj][r]);
    __syncthreads();

    const int d = tid >> 1, halfi = tid & 1;
    short* dst = vtg + ((size_t)(b * HKV_ + (hh - 20)) * DH_ + d) * N_ +
                 seq0 + halfi * 64;
#pragma unroll
    for (int c = 0; c < 8; ++c)
      *(frag16*)(dst + c * 8) = *(const frag16*)&T[d * 136 + halfi * 64 + c * 8];
  }
}

// ---------------------------------------------------------------------------
// bf16 MFMA GEMM (out-proj; unchanged m97-plateau structure)
// ---------------------------------------------------------------------------
template <typename OutT>
__global__ __launch_bounds__(256) void gemm_mfma(const short* __restrict__ A,
                                                 const short* __restrict__ Wt,
                                                 OutT* __restrict__ C,
                                                 int Nc, int K, int ncpx) {
  __shared__ __align__(16) short As[128][64];
  __shared__ __align__(16) short Bs[128][64];

  const int bid = blockIdx.x;
  const int xcd = bid & 7, j = bid >> 3;
  const int m0 = (j & 31) * 128;
  const int n0 = (xcd * ncpx + (j >> 5)) * 128;

  const int tid = threadIdx.x;
  const int lane = tid & 63;
  const int w = tid >> 6;
  const int ln = lane & 15, g = lane >> 4;
  const int wm = (w >> 1) * 64, wn = (w & 1) * 64;

  const int srow = lane >> 3;
  const int schunk = ((lane & 7) ^ srow) * 8;
  const int l7 = ln & 7;

  fragf4 acc[4][4];
#pragma unroll
  for (int i = 0; i < 4; ++i)
#pragma unroll
    for (int jj = 0; jj < 4; ++jj) acc[i][jj] = (fragf4){0.f, 0.f, 0.f, 0.f};

  for (int k0 = 0; k0 < K; k0 += 64) {
    __syncthreads();
#pragma unroll
    for (int i = 0; i < 4; ++i) {
      const int rbase = w * 32 + i * 8;
      const int r = rbase + srow;
      async_copy16(A  + (size_t)(m0 + r) * K + k0 + schunk, &As[rbase][0]);
      async_copy16(Wt + (size_t)(n0 + r) * K + k0 + schunk, &Bs[rbase][0]);
    }
    __syncthreads();

    frag16 af[2][4], bf[2][4];
#pragma unroll
    for (int c = 0; c < 2; ++c) {
      const int pc = (((c << 2) | g) ^ l7) * 8;
#pragma unroll
      for (int t = 0; t < 4; ++t) {
        af[c][t] = *(const frag16*)&As[wm + t * 16 + ln][pc];
        bf[c][t] = *(const frag16*)&Bs[wn + t * 16 + ln][pc];
      }
    }
#pragma unroll
    for (int c = 0; c < 2; ++c)
#pragma unroll
      for (int i = 0; i < 4; ++i)
#pragma unroll
        for (int jj = 0; jj < 4; ++jj)
          acc[i][jj] = MFMA16(af[c][i], bf[c][jj], acc[i][jj]);
  }

#pragma unroll
  for (int i = 0; i < 4; ++i) {
#pragma unroll
    for (int jj = 0; jj < 4; ++jj) {
#pragma unroll
      for (int r = 0; r < 4; ++r) {
        const size_t idx = (size_t)(m0 + wm + i * 16 + 4 * g + r) * Nc +
                           (n0 + wn + jj * 16 + ln);
        if constexpr (sizeof(OutT) == 2) C[idx] = f2bf(acc[i][jj][r]);
        else                             C[idx] = acc[i][jj][r];
      }
    }
  }
}

// ---------------------------------------------------------------------------
// bf16-MFMA flash attention (unchanged from round 7)
// ---------------------------------------------------------------------------
__global__ __launch_bounds__(256) void attn_mfma(const short* __restrict__ qkvb,
                                                 const short* __restrict__ vtg,
                                                 short* __restrict__ yb) {
  const int bx = blockIdx.x;
  const int qt2 = 31 - (bx >> 4);
  const int id = bx & 15;
  const int kh = id & 3, b = id >> 2;
  const int q0 = qt2 * 32;

  __shared__ __align__(16) short lds_[27648];
  const int VT0 = 8192, PS0 = 16384;

  const int tid = threadIdx.x;
  const int lane = tid & 63;
  const int w = tid >> 6;
  const int ln = lane & 15, g = lane >> 4, g8 = g * 8, l7 = ln & 7;
  const int h = kh * 4 + w;
  const int psw = PS0 + w * 2816;

  const short* qb = qkvb + (size_t)b * N_ * E_ + h * DH_;
  const short* kb = qkvb + (size_t)b * N_ * E_ + D_ + kh * DH_;
  const short* vt = vtg + (size_t)(b * HKV_ + kh) * DH_ * N_;

  frag16 qf[2][4];
#pragma unroll
  for (int t = 0; t < 2; ++t) {
    const short* qrow = qb + (size_t)(q0 + 16 * t + ln) * E_ + g8;
#pragma unroll
    for (int c = 0; c < 4; ++c) qf[t][c] = *(const frag16*)(qrow + c * 32);
  }

  frag16 ones;
#pragma unroll
  for (int jx = 0; jx < 8; ++jx) ones[jx] = (short)0x3F80;

  fragf4 o[2][8], ol[2];
#pragma unroll
  for (int t = 0; t < 2; ++t) {
    ol[t] = (fragf4){0.f, 0.f, 0.f, 0.f};
#pragma unroll
    for (int dt = 0; dt < 8; ++dt) o[t][dt] = (fragf4){0.f, 0.f, 0.f, 0.f};
  }

  const float SC2 = (float)(SCALE_ * 1.4426950408889634);
  const float MB2 = (float)(12.0 * 1.4426950408889634);

  const int krow = tid >> 2, kgrp = tid & 3;
  const int vrow = tid >> 1, vgrp = tid & 1;

  const int ntiles = (q0 + 95) >> 6;
  for (int kt = 0; kt < ntiles; ++kt) {
    const int kbase = kt * 64;
    __syncthreads();
    {
      const short* src = kb + (size_t)(kbase + krow) * E_ + kgrp * 32;
      const int r7 = krow & 7;
#pragma unroll
      for (int i = 0; i < 4; ++i) {
        const int lc = kgrp * 4 + i;
        *(frag16*)&lds_[krow * 128 + (lc ^ r7) * 8] = *(const frag16*)(src + i * 8);
      }
    }
    {
      const short* src = vt + (size_t)vrow * N_ + kbase + vgrp * 32;
      const int r7 = vrow & 7;
#pragma unroll
      for (int i = 0; i < 4; ++i) {
        const int lc = vgrp * 4 + i;
        *(frag16*)&lds_[VT0 + vrow * 64 + (lc ^ r7) * 8] = *(const frag16*)(src + i * 8);
      }
    }
    __syncthreads();

    fragf4 s[2][4];
#pragma unroll
    for (int t = 0; t < 2; ++t)
#pragma unroll
      for (int st = 0; st < 4; ++st) s[t][st] = (fragf4){0.f, 0.f, 0.f, 0.f};
#pragma unroll
    for (int c = 0; c < 4; ++c) {
      const int pc = ((c * 4 + g) ^ l7) * 8;
#pragma unroll
      for (int st = 0; st < 4; ++st) {
        frag16 kf = *(const frag16*)&lds_[(st * 16 + ln) * 128 + pc];
        s[0][st] = MFMA16(qf[0][c], kf, s[0][st]);
        s[1][st] = MFMA16(qf[1][c], kf, s[1][st]);
      }
    }

#pragma unroll
    for (int t = 0; t < 2; ++t) {
      const int qbase = q0 + 16 * t;
      const bool full = (kbase + 63) <= qbase;
#pragma unroll
      for (int st = 0; st < 4; ++st) {
        const int kg = kbase + st * 16 + ln;
        const int po = psw + (st >> 1) * 48 + (st & 1) * 16 + ln;
#pragma unroll
        for (int r2 = 0; r2 < 4; ++r2) {
          float sv = s[t][st][r2];
          if (!full && kg > qbase + 4 * g + r2) sv = -1.0e30f;
          const float p = exp2f(fmaf(sv, SC2, -MB2));
          lds_[po + (16 * t + 4 * g + r2) * 88] = f2bf_t(p);
        }
      }
    }

    frag16 pf[2][2];
#pragma unroll
    for (int t = 0; t < 2; ++t)
#pragma unroll
      for (int hh = 0; hh < 2; ++hh)
        pf[t][hh] = *(const frag16*)&lds_[psw + (16 * t + ln) * 88 + hh * 48 + g8];
#pragma unroll
    for (int dt = 0; dt < 8; ++dt) {
#pragma unroll
      for (int hh = 0; hh < 2; ++hh) {
        const int pv = ((hh * 4 + g) ^ l7) * 8;
        frag16 vf = *(const frag16*)&lds_[VT0 + (dt * 16 + ln) * 64 + pv];
        o[0][dt] = MFMA16(pf[0][hh], vf, o[0][dt]);
        o[1][dt] = MFMA16(pf[1][hh], vf, o[1][dt]);
      }
    }
#pragma unroll
    for (int t = 0; t < 2; ++t) {
      ol[t] = MFMA16(pf[t][0], ones, ol[t]);
      ol[t] = MFMA16(pf[t][1], ones, ol[t]);
    }
  }

#pragma unroll
  for (int t = 0; t < 2; ++t) {
#pragma unroll
    for (int r2 = 0; r2 < 4; ++r2) {
      const float inv = 1.0f / ol[t][r2];
      short* yrow = yb + ((size_t)b * N_ + q0 + 16 * t + 4 * g + r2) * D_ + h * DH_;
#pragma unroll
      for (int dt = 0; dt < 8; ++dt) yrow[dt * 16 + ln] = f2bf(o[t][dt][r2] * inv);
    }
  }
}

// ---------------------------------------------------------------------------
extern "C" void kernel_launch(void* const* d_in, const int* in_sizes, int n_in,
                              void* d_out, int out_size, void* d_ws, size_t ws_size,
                              hipStream_t stream) {
  const float* x     = (const float*)d_in[0];
  const int*   pos   = (const int*)d_in[2];
  const float* w_qkv = (const float*)d_in[3];
  const float* w_out = (const float*)d_in[4];
  const float* qw    = (const float*)d_in[5];
  const float* kw    = (const float*)d_in[6];
  float* out = (float*)d_out;

  short* qkvb = (short*)d_ws;
  short* yb   = qkvb + (size_t)B_ * N_ * E_;
  short* xb   = yb   + (size_t)B_ * N_ * D_;
  short* wqb  = xb   + (size_t)B_ * N_ * D_;
  short* wob  = wqb  + (size_t)E_ * D_;

  // vtg (4.2 MB) + rope table (0.5 MB) live in d_out's slack: gemm2 fully
  // overwrites d_out afterwards, and all reads of vtg/tab precede gemm2.
  short*  vtg = (short*)d_out;
  float2* tab = (float2*)((short*)d_out + 2097152);

  const int bx_ = (B_ * N_ * D_) / 2048;   // 4096
  const int bwq = (E_ * D_) / 2048;        // 3072
  const int bwo = (D_ * D_) / 2048;        // 2048
  f2bf3r<<<bx_ + bwq + bwo + 256, 256, 0, stream>>>(
      x, xb, bx_, w_qkv, wqb, bwq, w_out, wob, bwo, pos, tab);

  gemm_qkv<<<768, 256, 0, stream>>>(xb, wqb, qkvb, vtg, tab, qw, kw);

  attn_mfma<<<512, 256, 0, stream>>>(qkvb, vtg, yb);

  gemm_mfma<float><<<512, 256, 0, stream>>>(yb, wob, out, D_, D_, 2);
}

// Round 9
// 304.545 us; speedup vs baseline: 1.0280x; 1.0169x over previous
//
#include <hip/hip_runtime.h>
#include <cstdint>
#include <cstddef>

#define B_   4
#define N_   1024
#define D_   2048
#define HQ_  16
#define HKV_ 4
#define DH_  128
#define E_   3072

#define SCALE_ 0.08838834764831845  // 128^-0.5

typedef __attribute__((ext_vector_type(8))) short frag16;
typedef __attribute__((ext_vector_type(4))) short short4v;
typedef __attribute__((ext_vector_type(4))) float fragf4;
#define MFMA16(a, b, c) __builtin_amdgcn_mfma_f32_16x16x32_bf16(a, b, c, 0, 0, 0)

__device__ __forceinline__ short f2bf(float f) {
  union { float f; uint32_t u; } a; a.f = f;
  uint32_t r = (a.u + 0x7fffu + ((a.u >> 16) & 1u)) >> 16;  // RNE
  return (short)r;
}
__device__ __forceinline__ short f2bf_t(float f) {  // truncate (p>=0)
  union { float f; uint32_t u; } a; a.f = f;
  return (short)(a.u >> 16);
}
__device__ __forceinline__ float bf2f(short s) {
  union { uint32_t u; float f; } a;
  a.u = ((uint32_t)(uint16_t)s) << 16;
  return a.f;
}
__device__ __forceinline__ void async_copy16(const void* g, void* l) {
  __builtin_amdgcn_global_load_lds(
      (const __attribute__((address_space(1))) void*)g,
      (__attribute__((address_space(3))) void*)l, 16, 0, 0);
}

// ---------------------------------------------------------------------------
// fused fp32->bf16 conversion (3 tensors) + RoPE cos/sin table, one launch.
// ---------------------------------------------------------------------------
__global__ __launch_bounds__(256) void f2bf3r(
    const float* __restrict__ s0, short* __restrict__ d0, int b0,
    const float* __restrict__ s1, short* __restrict__ d1, int b1,
    const float* __restrict__ s2, short* __restrict__ d2, int b2,
    const int* __restrict__ pos, float2* __restrict__ tab) {
  int bx = blockIdx.x;
  const int btot = b0 + b1 + b2;
  if (bx < btot) {
    const float* s; short* d;
    if (bx < b0)           { s = s0; d = d0; }
    else if (bx < b0 + b1) { s = s1; d = d1; bx -= b0; }
    else                   { s = s2; d = d2; bx -= b0 + b1; }
    const int i = (bx * 256 + threadIdx.x) * 8;
    float4 a = *(const float4*)(s + i);
    float4 b = *(const float4*)(s + i + 4);
    union { frag16 f; short sh[8]; } u;
    u.sh[0] = f2bf(a.x); u.sh[1] = f2bf(a.y); u.sh[2] = f2bf(a.z); u.sh[3] = f2bf(a.w);
    u.sh[4] = f2bf(b.x); u.sh[5] = f2bf(b.y); u.sh[6] = f2bf(b.z); u.sh[7] = f2bf(b.w);
    *(frag16*)(d + i) = u.f;
  } else {
    const int idx = (bx - btot) * 256 + threadIdx.x;  // 0..65535
    const int seq = idx >> 6, dd = idx & 63;
    const float invf = (float)exp2(-(double)dd * 0.20762050593046014);
    const float ang = (float)pos[seq] * invf;
    float2 cs; cs.x = cosf(ang); cs.y = sinf(ang);
    tab[idx] = cs;
  }
}

// ---------------------------------------------------------------------------
// QKV GEMM + fused RMSNorm/RoPE/V-transpose epilogue (slimmed).
// C-tile 128x128 = 128 seq positions x ONE head. K-loop = m97 structure.
// Epilogue q/k: fp32 rowwise rms (shuffle + Sred) -> bf16 tile T (stride 132)
// -> rope in wide ops (b64 LDS reads, b64 stores). v: transpose via T -> vtg.
// ---------------------------------------------------------------------------
__global__ __launch_bounds__(256) void gemm_qkv(
    const short* __restrict__ A, const short* __restrict__ Wt,
    short* __restrict__ qkvb, short* __restrict__ vtg,
    const float2* __restrict__ tab,
    const float* __restrict__ qw, const float* __restrict__ kw) {
  // carve: K-loop As[128][64]@0, Bs[128][64]@8192 (shorts)
  //        epilogue T[128][132]@0 (16896), Sred 256 floats @16896
  __shared__ __align__(16) short smem[17408];
  short* As = smem;
  short* Bs = smem + 8192;

  const int bid = blockIdx.x;
  const int xcd = bid & 7, j = bid >> 3;
  const int m0 = (j & 31) * 128;
  const int n0 = (xcd * 3 + (j >> 5)) * 128;

  const int tid = threadIdx.x;
  const int lane = tid & 63;
  const int w = tid >> 6;
  const int ln = lane & 15, g = lane >> 4;
  const int wm = (w >> 1) * 64, wn = (w & 1) * 64;

  const int srow = lane >> 3;
  const int schunk = ((lane & 7) ^ srow) * 8;
  const int l7 = ln & 7;

  fragf4 acc[4][4];
#pragma unroll
  for (int i = 0; i < 4; ++i)
#pragma unroll
    for (int jj = 0; jj < 4; ++jj) acc[i][jj] = (fragf4){0.f, 0.f, 0.f, 0.f};

  for (int k0 = 0; k0 < D_; k0 += 64) {
    __syncthreads();
#pragma unroll
    for (int i = 0; i < 4; ++i) {
      const int rbase = w * 32 + i * 8;
      const int r = rbase + srow;
      async_copy16(A  + (size_t)(m0 + r) * D_ + k0 + schunk, &As[rbase * 64]);
      async_copy16(Wt + (size_t)(n0 + r) * D_ + k0 + schunk, &Bs[rbase * 64]);
    }
    __syncthreads();

    frag16 af[2][4], bf[2][4];
#pragma unroll
    for (int c = 0; c < 2; ++c) {
      const int pc = (((c << 2) | g) ^ l7) * 8;
#pragma unroll
      for (int t = 0; t < 4; ++t) {
        af[c][t] = *(const frag16*)&As[(wm + t * 16 + ln) * 64 + pc];
        bf[c][t] = *(const frag16*)&Bs[(wn + t * 16 + ln) * 64 + pc];
      }
    }
#pragma unroll
    for (int c = 0; c < 2; ++c)
#pragma unroll
      for (int i = 0; i < 4; ++i)
#pragma unroll
        for (int jj = 0; jj < 4; ++jj)
          acc[i][jj] = MFMA16(af[c][i], bf[c][jj], acc[i][jj]);
  }

  // ---------------- fused epilogue ----------------
  const int hh = n0 >> 7;        // head 0..23 (0-15 q, 16-19 k, 20-23 v)
  const int b  = m0 >> 10;
  const int seq0 = m0 & 1023;
  short* T = smem;                       // [128][132]
  float* Sred = (float*)&smem[16896];    // [2][128]

  __syncthreads();  // all frag reads done before tile overwrite

  if (hh < 20) {
    // rowwise sum of squares (fp32 acc domain)
    float rs[4][4];
#pragma unroll
    for (int i = 0; i < 4; ++i)
#pragma unroll
      for (int r = 0; r < 4; ++r) {
        float t = 0.f;
#pragma unroll
        for (int jj = 0; jj < 4; ++jj) t += acc[i][jj][r] * acc[i][jj][r];
        rs[i][r] = t;
      }
#pragma unroll
    for (int off = 1; off <= 8; off <<= 1)
#pragma unroll
      for (int i = 0; i < 4; ++i)
#pragma unroll
        for (int r = 0; r < 4; ++r) rs[i][r] += __shfl_xor(rs[i][r], off);
    if (ln == 0) {
#pragma unroll
      for (int i = 0; i < 4; ++i)
#pragma unroll
        for (int r = 0; r < 4; ++r)
          Sred[(w & 1) * 128 + wm + i * 16 + 4 * g + r] = rs[i][r];
    }
    __syncthreads();

    const float* wnv = (hh < 16) ? qw : kw;
    float wv[4];
#pragma unroll
    for (int jj = 0; jj < 4; ++jj) wv[jj] = wnv[wn + jj * 16 + ln];
#pragma unroll
    for (int i = 0; i < 4; ++i)
#pragma unroll
      for (int r = 0; r < 4; ++r) {
        const int row = wm + i * 16 + 4 * g + r;
        const float tot = Sred[row] + Sred[128 + row];
        const float rms = rsqrtf(tot * (1.0f / 128.0f) + 1.1920928955078125e-07f);
#pragma unroll
        for (int jj = 0; jj < 4; ++jj)
          T[row * 132 + wn + jj * 16 + ln] = f2bf(acc[i][jj][r] * rms * wv[jj]);
      }
    __syncthreads();

    // rope: thread = (d-quad = tid&15, row-group = tid>>4); 8 rows x 4 pairs
    const int d0 = (tid & 15) * 4, rt = tid >> 4;
#pragma unroll
    for (int rr = 0; rr < 8; ++rr) {
      const int row = rt * 8 + rr;
      short4v lo = *(const short4v*)&T[row * 132 + d0];
      short4v hi = *(const short4v*)&T[row * 132 + d0 + 64];
      float4 cs01 = *(const float4*)&tab[(seq0 + row) * 64 + d0];
      float4 cs23 = *(const float4*)&tab[(seq0 + row) * 64 + d0 + 2];
      float c[4] = {cs01.x, cs01.z, cs23.x, cs23.z};
      float s[4] = {cs01.y, cs01.w, cs23.y, cs23.w};
      short4v olo, ohi;
#pragma unroll
      for (int q = 0; q < 4; ++q) {
        const float a = bf2f(lo[q]), bb = bf2f(hi[q]);
        olo[q] = f2bf(a * c[q] - bb * s[q]);
        ohi[q] = f2bf(bb * c[q] + a * s[q]);
      }
      short* dst = qkvb + ((size_t)b * N_ + seq0 + row) * E_ + hh * DH_ + d0;
      *(short4v*)dst = olo;
      *(short4v*)(dst + 64) = ohi;
    }
  } else {
    // v head: transpose via T, coalesced rows to vtg
#pragma unroll
    for (int i = 0; i < 4; ++i)
#pragma unroll
      for (int jj = 0; jj < 4; ++jj)
#pragma unroll
        for (int r = 0; r < 4; ++r)
          T[(wn + jj * 16 + ln) * 132 + wm + i * 16 + 4 * g + r] =
              f2bf(acc[i][jj][r]);
    __syncthreads();

    const int d = tid >> 1, halfi = tid & 1;
    short* dst = vtg + ((size_t)(b * HKV_ + (hh - 20)) * DH_ + d) * N_ +
                 seq0 + halfi * 64;
#pragma unroll
    for (int c = 0; c < 8; ++c)
      *(frag16*)(dst + c * 8) = *(const frag16*)&T[d * 132 + halfi * 64 + c * 8];
  }
}

// ---------------------------------------------------------------------------
// bf16 MFMA GEMM (out-proj; unchanged m97-plateau structure)
// ---------------------------------------------------------------------------
template <typename OutT>
__global__ __launch_bounds__(256) void gemm_mfma(const short* __restrict__ A,
                                                 const short* __restrict__ Wt,
                                                 OutT* __restrict__ C,
                                                 int Nc, int K, int ncpx) {
  __shared__ __align__(16) short As[128][64];
  __shared__ __align__(16) short Bs[128][64];

  const int bid = blockIdx.x;
  const int xcd = bid & 7, j = bid >> 3;
  const int m0 = (j & 31) * 128;
  const int n0 = (xcd * ncpx + (j >> 5)) * 128;

  const int tid = threadIdx.x;
  const int lane = tid & 63;
  const int w = tid >> 6;
  const int ln = lane & 15, g = lane >> 4;
  const int wm = (w >> 1) * 64, wn = (w & 1) * 64;

  const int srow = lane >> 3;
  const int schunk = ((lane & 7) ^ srow) * 8;
  const int l7 = ln & 7;

  fragf4 acc[4][4];
#pragma unroll
  for (int i = 0; i < 4; ++i)
#pragma unroll
    for (int jj = 0; jj < 4; ++jj) acc[i][jj] = (fragf4){0.f, 0.f, 0.f, 0.f};

  for (int k0 = 0; k0 < K; k0 += 64) {
    __syncthreads();
#pragma unroll
    for (int i = 0; i < 4; ++i) {
      const int rbase = w * 32 + i * 8;
      const int r = rbase + srow;
      async_copy16(A  + (size_t)(m0 + r) * K + k0 + schunk, &As[rbase][0]);
      async_copy16(Wt + (size_t)(n0 + r) * K + k0 + schunk, &Bs[rbase][0]);
    }
    __syncthreads();

    frag16 af[2][4], bf[2][4];
#pragma unroll
    for (int c = 0; c < 2; ++c) {
      const int pc = (((c << 2) | g) ^ l7) * 8;
#pragma unroll
      for (int t = 0; t < 4; ++t) {
        af[c][t] = *(const frag16*)&As[wm + t * 16 + ln][pc];
        bf[c][t] = *(const frag16*)&Bs[wn + t * 16 + ln][pc];
      }
    }
#pragma unroll
    for (int c = 0; c < 2; ++c)
#pragma unroll
      for (int i = 0; i < 4; ++i)
#pragma unroll
        for (int jj = 0; jj < 4; ++jj)
          acc[i][jj] = MFMA16(af[c][i], bf[c][jj], acc[i][jj]);
  }

#pragma unroll
  for (int i = 0; i < 4; ++i) {
#pragma unroll
    for (int jj = 0; jj < 4; ++jj) {
#pragma unroll
      for (int r = 0; r < 4; ++r) {
        const size_t idx = (size_t)(m0 + wm + i * 16 + 4 * g + r) * Nc +
                           (n0 + wn + jj * 16 + ln);
        if constexpr (sizeof(OutT) == 2) C[idx] = f2bf(acc[i][jj][r]);
        else                             C[idx] = acc[i][jj][r];
      }
    }
  }
}

// ---------------------------------------------------------------------------
// bf16-MFMA flash attention — round-6 v2.5 (restored): 16 q-rows/wave, KT=64,
// 24 KB LDS -> 6 blocks/CU, grid 1024 LPT.
// ---------------------------------------------------------------------------
__global__ __launch_bounds__(256) void attn_mfma(const short* __restrict__ qkvb,
                                                 const short* __restrict__ vtg,
                                                 short* __restrict__ yb) {
  const int bx = blockIdx.x;
  const int qt = 63 - (bx >> 4);
  const int id = bx & 15;
  const int kh = id & 3, b = id >> 2;
  const int q0 = qt * 16;

  __shared__ __align__(16) short lds_[22600];
  const int VT0 = 8704, PS0 = 17992;

  const int tid = threadIdx.x;
  const int lane = tid & 63;
  const int w = tid >> 6;
  const int ln = lane & 15, g = lane >> 4, g8 = g * 8;
  const int h = kh * 4 + w;

  const short* qb = qkvb + (size_t)b * N_ * E_ + h * DH_;
  const short* kb = qkvb + (size_t)b * N_ * E_ + D_ + kh * DH_;
  const short* vt = vtg + (size_t)(b * HKV_ + kh) * DH_ * N_;

  if (tid < 64) lds_[VT0 + 128 * 72 + tid] = (short)0x3F80;

  frag16 qf[4];
  {
    const short* qrow = qb + (size_t)(q0 + ln) * E_ + g8;
#pragma unroll
    for (int c = 0; c < 4; ++c) qf[c] = *(const frag16*)(qrow + c * 32);
  }

  fragf4 o[8], ol = (fragf4){0.f, 0.f, 0.f, 0.f};
#pragma unroll
  for (int dt = 0; dt < 8; ++dt) o[dt] = (fragf4){0.f, 0.f, 0.f, 0.f};

  const float SC2 = (float)(SCALE_ * 1.4426950408889634);
  const float MB2 = (float)(12.0 * 1.4426950408889634);

  const int ntiles = qt / 4 + 1;
  for (int kt = 0; kt < ntiles; ++kt) {
    const int kbase = kt * 64;
    __syncthreads();
    {
      const int r = tid & 63, c = (tid >> 6) * 32;
      const short* src = kb + (size_t)(kbase + r) * E_ + c;
#pragma unroll
      for (int i = 0; i < 4; ++i)
        *(frag16*)&lds_[r * 136 + c + 8 * i] = *(const frag16*)(src + 8 * i);
    }
    {
      const int d = tid & 127, e = tid >> 7;
      const short* src = vt + (size_t)d * N_ + kbase + e * 32;
#pragma unroll
      for (int i = 0; i < 4; ++i)
        *(frag16*)&lds_[VT0 + d * 72 + e * 32 + 8 * i] = *(const frag16*)(src + 8 * i);
    }
    __syncthreads();

    fragf4 s[4];
#pragma unroll
    for (int st = 0; st < 4; ++st) s[st] = (fragf4){0.f, 0.f, 0.f, 0.f};
#pragma unroll
    for (int c = 0; c < 4; ++c) {
      frag16 qc = qf[c];
#pragma unroll
      for (int st = 0; st < 4; ++st) {
        frag16 kf = *(const frag16*)&lds_[(st * 16 + ln) * 136 + c * 32 + g8];
        s[st] = MFMA16(qc, kf, s[st]);
      }
    }

    const bool full = (kbase + 63) <= q0;
#pragma unroll
    for (int st = 0; st < 4; ++st) {
      const int kg = kbase + st * 16 + ln;
#pragma unroll
      for (int r2 = 0; r2 < 4; ++r2) {
        float sv = s[st][r2];
        if (!full && kg > q0 + 4 * g + r2) sv = -1.0e30f;
        const float p = exp2f(fmaf(sv, SC2, -MB2));
        lds_[PS0 + (w * 16 + 4 * g + r2) * 72 + st * 16 + ln] = f2bf_t(p);
      }
    }

    frag16 pf0 = *(const frag16*)&lds_[PS0 + (w * 16 + ln) * 72 + g8];
    frag16 pf1 = *(const frag16*)&lds_[PS0 + (w * 16 + ln) * 72 + 32 + g8];
#pragma unroll
    for (int dt = 0; dt < 8; ++dt) {
      frag16 v0 = *(const frag16*)&lds_[VT0 + (dt * 16 + ln) * 72 + g8];
      frag16 v1 = *(const frag16*)&lds_[VT0 + (dt * 16 + ln) * 72 + 32 + g8];
      o[dt] = MFMA16(pf0, v0, o[dt]);
      o[dt] = MFMA16(pf1, v1, o[dt]);
    }
    {
      frag16 vl0 = *(const frag16*)&lds_[VT0 + (128 + ln) * 72 + g8];
      frag16 vl1 = *(const frag16*)&lds_[VT0 + (128 + ln) * 72 + 32 + g8];
      ol = MFMA16(pf0, vl0, ol);
      ol = MFMA16(pf1, vl1, ol);
    }
  }

#pragma unroll
  for (int r2 = 0; r2 < 4; ++r2) {
    const float lv = __shfl(ol[r2], lane & 48);
    const float inv = 1.0f / lv;
    short* yrow = yb + ((size_t)b * N_ + q0 + 4 * g + r2) * D_ + h * DH_;
#pragma unroll
    for (int dt = 0; dt < 8; ++dt) yrow[dt * 16 + ln] = f2bf(o[dt][r2] * inv);
  }
}

// ---------------------------------------------------------------------------
extern "C" void kernel_launch(void* const* d_in, const int* in_sizes, int n_in,
                              void* d_out, int out_size, void* d_ws, size_t ws_size,
                              hipStream_t stream) {
  const float* x     = (const float*)d_in[0];
  const int*   pos   = (const int*)d_in[2];
  const float* w_qkv = (const float*)d_in[3];
  const float* w_out = (const float*)d_in[4];
  const float* qw    = (const float*)d_in[5];
  const float* kw    = (const float*)d_in[6];
  float* out = (float*)d_out;

  short* qkvb = (short*)d_ws;
  short* yb   = qkvb + (size_t)B_ * N_ * E_;
  short* xb   = yb   + (size_t)B_ * N_ * D_;
  short* wqb  = xb   + (size_t)B_ * N_ * D_;
  short* wob  = wqb  + (size_t)E_ * D_;

  // vtg (4.2 MB) + rope table (0.5 MB) in d_out slack (gemm2 overwrites later)
  short*  vtg = (short*)d_out;
  float2* tab = (float2*)((short*)d_out + 2097152);

  const int bx_ = (B_ * N_ * D_) / 2048;   // 4096
  const int bwq = (E_ * D_) / 2048;        // 3072
  const int bwo = (D_ * D_) / 2048;        // 2048
  f2bf3r<<<bx_ + bwq + bwo + 256, 256, 0, stream>>>(
      x, xb, bx_, w_qkv, wqb, bwq, w_out, wob, bwo, pos, tab);

  gemm_qkv<<<768, 256, 0, stream>>>(xb, wqb, qkvb, vtg, tab, qw, kw);

  attn_mfma<<<1024, 256, 0, stream>>>(qkvb, vtg, yb);

  gemm_mfma<float><<<512, 256, 0, stream>>>(yb, wob, out, D_, D_, 2);
}